// Round 12
// baseline (38.953 us; speedup 1.0000x reference)
//
#include <hip/hip_runtime.h>

typedef short bf16x8 __attribute__((ext_vector_type(8)));
typedef float f32x4  __attribute__((ext_vector_type(4)));

static constexpr int KH = 15, KW = 15;
static constexpr int HI = 4096, WI = 4096;
static constexpr int HO = HI - KH + 1, WO = WI - KW + 1;   // 4082 x 4082
static constexpr int TM = 64, TN = 128;                    // output tile
static constexpr int NT = 2;                               // tiles marched per block
static constexpr int LR   = TM + KH - 1;                   // 78 staged rows
static constexpr int LC   = 144;                           // staged bf16 cols
static constexpr int LSTR = 152;                           // 304 B/row base stride
static constexpr int IPR   = LC / 4;                       // 36 float4 items/row
static constexpr int ITEMS = LR * IPR;                     // 2808
static constexpr int SITER = (ITEMS + 511) / 512;          // 6 per thread
static constexpr int NSLOT = 23;                           // compact B slot table (slot 22 = zeros)
static constexpr int BKH   = NSLOT * 8;                    // 184 shorts per kh

// staggered row base (shorts): +16B per 16-row group so the 4 m-block reads
// land on different bank quads (R11 post-mortem: identical footprints -> 4.3e6 conflicts)
__device__ __forceinline__ int rowbase(int r) { return r * LSTR + ((r >> 4) << 3); }

__device__ __forceinline__ unsigned int f2bf(float f) {
  unsigned int u = __builtin_bit_cast(unsigned int, f);
  return (u + 0x7FFFu + ((u >> 16) & 1u)) >> 16;
}

__device__ __forceinline__ unsigned int cvt_pk_bf16(float lo, float hi) {
  unsigned int r;
  asm("v_cvt_pk_bf16_f32 %0, %1, %2" : "=v"(r) : "v"(lo), "v"(hi));
  return r;
}

__device__ __forceinline__ float4 load_item(const float* __restrict__ x,
                                            int row0, int col0, int it) {
  float4 v = make_float4(0.f, 0.f, 0.f, 0.f);
  if (it < ITEMS) {
    const int r  = it / IPR;
    const int c4 = (it - r * IPR) * 4;
    const int gr = row0 + r;
    const int gc = col0 + c4;
    if (gr < HI) {
      const float* p = &x[(long)gr * WI + gc];
      if (gc + 3 < WI) {
        v = *(const float4*)p;
      } else {
        if (gc + 0 < WI) v.x = p[0];
        if (gc + 1 < WI) v.y = p[1];
        if (gc + 2 < WI) v.z = p[2];
        if (gc + 3 < WI) v.w = p[3];
      }
    }
  }
  return v;
}

__device__ __forceinline__ void write_item(unsigned short* sx, int it, float4 v) {
  if (it < ITEMS) {
    const int r  = it / IPR;
    const int c4 = (it - r * IPR) * 4;
    *(uint2*)&sx[rowbase(r) + c4] = make_uint2(cvt_pk_bf16(v.x, v.y), cvt_pk_bf16(v.z, v.w));
  }
}

#define MFMA16(a, b, c) __builtin_amdgcn_mfma_f32_16x16x32_bf16((a), (b), (c), 0, 0, 0)

__global__ __launch_bounds__(512, 4)
void conv2d_tr(const float* __restrict__ x, const float* __restrict__ w,
               const float* __restrict__ bias, float* __restrict__ out) {
  __shared__ unsigned short sx[LR * LSTR + 64];   // 23,840 B staggered input tile
  __shared__ unsigned short btab[KH * BKH];       //  5,520 B compact clamp-slot weights

  const int tid = threadIdx.x;

  // XCD-aware bijective swizzle (1024 blocks, 1024 % 8 == 0)
  const int bid0  = blockIdx.y * gridDim.x + blockIdx.x;
  const int bid   = (bid0 & 7) * 128 + (bid0 >> 3);
  const int col0  = (bid & 31) * TN;
  const int rbase = (bid >> 5) * (NT * TM);

  // ---- compact weight table: btab[kh][s][t] = w[kh, s-7+t] if 0 <= s-7+t < 15 else 0
  for (int i = tid; i < KH * NSLOT; i += 512) {
    const int kh = i / NSLOT;
    const int s  = i - kh * NSLOT;
    const int e0 = s - 7;
    unsigned int dw[4];
    #pragma unroll
    for (int t2 = 0; t2 < 4; ++t2) {
      const int c0 = e0 + 2 * t2;
      const int c1 = c0 + 1;
      const unsigned int b0 = (c0 >= 0 && c0 < KW) ? f2bf(w[kh * KW + c0]) : 0u;
      const unsigned int b1 = (c1 >= 0 && c1 < KW) ? f2bf(w[kh * KW + c1]) : 0u;
      dw[t2] = b0 | (b1 << 16);
    }
    *(uint4*)&btab[i * 8] = make_uint4(dw[0], dw[1], dw[2], dw[3]);
  }

  // ---- stage tile 0 ----
  {
    float4 v0_[SITER];
    #pragma unroll
    for (int k = 0; k < SITER; ++k) v0_[k] = load_item(x, rbase, col0, tid + 512 * k);
    #pragma unroll
    for (int k = 0; k < SITER; ++k) write_item(sx, tid + 512 * k, v0_[k]);
  }
  const float bs = bias[0];
  __syncthreads();

  // ---- per-wave setup: wave wv -> output cols [wv*16, wv*16+16) ----
  // Transposed MFMA: D = A*B with A = weight band (registers), B = x slice (LDS).
  // A[j, p]: j = lane&15 (out col), p = 8*(lane>>4)+t  ->  w[kh, p-j]
  // B[p, i]: i = lane&15 (out row), p = 8*(lane>>4)+t  ->  x[i0+i+kh, cw+p]
  // D[j, i]: col=lane&15 = i, row = 4*(lane>>4)+reg = j -> 4 consecutive out cols/lane
  const int lane = tid & 63;
  const int wv   = tid >> 6;
  const int l15  = lane & 15;                 // plays j in A, i in B/D
  const int kg4  = lane >> 4;

  // weight fragments, register resident for the whole kernel
  const int e = 8 * kg4 - l15;                // p0 - j
  const int s = (e >= -7 && e <= 14) ? e + 7 : 22;
  bf16x8 wf[KH];
  #pragma unroll
  for (int kh = 0; kh < KH; ++kh)
    wf[kh] = *(const bf16x8*)&btab[s * 8 + kh * BKH];

  const int colsh = wv * 16 + kg4 * 8;        // x col chunk (shorts)
  const int ocb   = col0 + wv * 16 + kg4 * 4; // out col base (4 cols/lane)

  #pragma unroll
  for (int t = 0; t < NT; ++t) {
    const int trow0 = rbase + t * TM;

    f32x4 acc0 = {bs,bs,bs,bs}, acc1 = {bs,bs,bs,bs};
    f32x4 acc2 = {bs,bs,bs,bs}, acc3 = {bs,bs,bs,bs};

    __builtin_amdgcn_s_setprio(1);
    #pragma unroll
    for (int kh = 0; kh < 15; ++kh) {
      // row = 16m + l15 + kh; rowbase(16m+rr) = rowbase(rr) + m*(16*LSTR + 8)
      const unsigned short* ar = &sx[rowbase(l15 + kh) + colsh];
      acc0 = MFMA16(wf[kh], *(const bf16x8*)(ar + 0 * (16 * LSTR + 8)), acc0);
      acc1 = MFMA16(wf[kh], *(const bf16x8*)(ar + 1 * (16 * LSTR + 8)), acc1);
      acc2 = MFMA16(wf[kh], *(const bf16x8*)(ar + 2 * (16 * LSTR + 8)), acc2);
      acc3 = MFMA16(wf[kh], *(const bf16x8*)(ar + 3 * (16 * LSTR + 8)), acc3);
    }
    __builtin_amdgcn_s_setprio(0);

    // ---- store: lane holds out[trow0+16m+l15, ocb..ocb+3] per acc_m ----
    {
      const f32x4 av[4] = {acc0, acc1, acc2, acc3};
      #pragma unroll
      for (int m = 0; m < 4; ++m) {
        const int orow = trow0 + 16 * m + l15;
        if (orow < HO) {
          float* po = &out[(long)orow * WO + ocb];
          if (ocb + 3 < WO) {               // 8B-aligned pair stores
            *(float2*)(po + 0) = make_float2(av[m][0], av[m][1]);
            *(float2*)(po + 2) = make_float2(av[m][2], av[m][3]);
          } else {
            #pragma unroll
            for (int r = 0; r < 4; ++r)
              if (ocb + r < WO) po[r] = av[m][r];
          }
        }
      }
    }

    // rotate the single LDS buffer for the next tile
    if (t + 1 < NT) {
      float4 nv[SITER];
      #pragma unroll
      for (int k = 0; k < SITER; ++k)
        nv[k] = load_item(x, trow0 + TM, col0, tid + 512 * k);
      __syncthreads();                       // everyone done reading sx
      #pragma unroll
      for (int k = 0; k < SITER; ++k) write_item(sx, tid + 512 * k, nv[k]);
      __syncthreads();                       // next tile visible
    }
  }
}

extern "C" void kernel_launch(void* const* d_in, const int* in_sizes, int n_in,
                              void* d_out, int out_size, void* d_ws, size_t ws_size,
                              hipStream_t stream) {
  const float* x    = (const float*)d_in[0];
  const float* w    = (const float*)d_in[1];
  const float* bias = (const float*)d_in[2];
  float* out        = (float*)d_out;

  dim3 grid(32, 32);   // 1024 blocks: 32 col-strips x 32 row-bands (2 tiles each)
  conv2d_tr<<<grid, dim3(512, 1, 1), 0, stream>>>(x, w, bias, out);
}

// Round 14
// 34.555 us; speedup vs baseline: 1.1273x; 1.1273x over previous
//
#include <hip/hip_runtime.h>

typedef short bf16x8 __attribute__((ext_vector_type(8)));
typedef float f32x4  __attribute__((ext_vector_type(4)));

static constexpr int KH = 15, KW = 15;
static constexpr int HI = 4096, WI = 4096;
static constexpr int HO = HI - KH + 1, WO = WI - KW + 1;   // 4082 x 4082
static constexpr int TM = 64, TN = 128;                    // output tile
static constexpr int NT = 2;                               // tiles marched per block
static constexpr int LR   = TM + KH - 1;                   // 78 staged rows
static constexpr int LC   = 144;                           // staged bf16 cols (18 chunks of 16B)
static constexpr int LSTR = 192;                           // 384 B/row: 24 chunk slots (XOR space for 18 used)
static constexpr int IPR   = LC / 4;                       // 36 float4 items/row
static constexpr int ITEMS = LR * IPR;                     // 2808
static constexpr int SITER = (ITEMS + 511) / 512;          // 6 per thread
static constexpr int NSLOT = 23;                           // compact B slot table (slot 22 = zeros)
static constexpr int BKH   = NSLOT * 8;                    // 184 shorts per kh

__device__ __forceinline__ unsigned int f2bf(float f) {
  unsigned int u = __builtin_bit_cast(unsigned int, f);
  return (u + 0x7FFFu + ((u >> 16) & 1u)) >> 16;
}

__device__ __forceinline__ unsigned int cvt_pk_bf16(float lo, float hi) {
  unsigned int r;
  asm("v_cvt_pk_bf16_f32 %0, %1, %2" : "=v"(r) : "v"(lo), "v"(hi));
  return r;
}

__device__ __forceinline__ float4 load_item(const float* __restrict__ x,
                                            int row0, int col0, int it) {
  float4 v = make_float4(0.f, 0.f, 0.f, 0.f);
  if (it < ITEMS) {
    const int r  = it / IPR;
    const int c4 = (it - r * IPR) * 4;
    const int gr = row0 + r;
    const int gc = col0 + c4;
    if (gr < HI) {
      const float* p = &x[(long)gr * WI + gc];
      if (gc + 3 < WI) {
        v = *(const float4*)p;
      } else {
        if (gc + 0 < WI) v.x = p[0];
        if (gc + 1 < WI) v.y = p[1];
        if (gc + 2 < WI) v.z = p[2];
        if (gc + 3 < WI) v.w = p[3];
      }
    }
  }
  return v;
}

// chunk-XOR swizzled write: 16B chunk c of row r lives at physical chunk c ^ (r&7).
// c4 is an ELEMENT offset (multiple of 4): chunk = c4>>3, in-chunk half = c4&4.
// Max ofs = 77*192 + 23*8 + 4 = 14,972 < 78*192 = 14,976 (in bounds).
__device__ __forceinline__ void write_item(unsigned short* sx, int it, float4 v) {
  if (it < ITEMS) {
    const int r  = it / IPR;
    const int c4 = (it - r * IPR) * 4;
    const int ch = (c4 >> 3) ^ (r & 7);
    const int ofs = r * LSTR + ch * 8 + (c4 & 4);
    *(uint2*)&sx[ofs] = make_uint2(cvt_pk_bf16(v.x, v.y), cvt_pk_bf16(v.z, v.w));
  }
}

#define MFMA16(a, b, c) __builtin_amdgcn_mfma_f32_16x16x32_bf16((a), (b), (c), 0, 0, 0)

__global__ __launch_bounds__(512, 4)
void conv2d_swz(const float* __restrict__ x, const float* __restrict__ w,
                const float* __restrict__ bias, float* __restrict__ out) {
  __shared__ unsigned short sx[LR * LSTR];        // 29,952 B swizzled input tile
  __shared__ unsigned short btab[KH * BKH];       //  5,520 B compact clamp-slot weights
  // total 35,472 B -> 4 blocks/CU (32 waves) still holds

  const int tid = threadIdx.x;

  // XCD-aware bijective swizzle (1024 blocks, 1024 % 8 == 0)
  const int bid0  = blockIdx.y * gridDim.x + blockIdx.x;
  const int bid   = (bid0 & 7) * 128 + (bid0 >> 3);
  const int col0  = (bid & 31) * TN;
  const int rbase = (bid >> 5) * (NT * TM);

  // ---- compact B table: btab[kh][s][t] = w[kh, s-7+t] if 0 <= s-7+t < 15 else 0
  for (int i = tid; i < KH * NSLOT; i += 512) {
    const int kh = i / NSLOT;
    const int s  = i - kh * NSLOT;
    const int e0 = s - 7;
    unsigned int dw[4];
    #pragma unroll
    for (int t2 = 0; t2 < 4; ++t2) {
      const int c0 = e0 + 2 * t2;
      const int c1 = c0 + 1;
      const unsigned int b0 = (c0 >= 0 && c0 < KW) ? f2bf(w[kh * KW + c0]) : 0u;
      const unsigned int b1 = (c1 >= 0 && c1 < KW) ? f2bf(w[kh * KW + c1]) : 0u;
      dw[t2] = b0 | (b1 << 16);
    }
    *(uint4*)&btab[i * 8] = make_uint4(dw[0], dw[1], dw[2], dw[3]);
  }

  // ---- stage tile 0 ----
  {
    float4 v0_[SITER];
    #pragma unroll
    for (int k = 0; k < SITER; ++k) v0_[k] = load_item(x, rbase, col0, tid + 512 * k);
    #pragma unroll
    for (int k = 0; k < SITER; ++k) write_item(sx, tid + 512 * k, v0_[k]);
  }
  const float bs = bias[0];
  __syncthreads();

  // ---- per-wave setup: wave wv -> output cols [wv*16, wv*16+16) ----
  const int lane = tid & 63;
  const int wv   = tid >> 6;
  const int q    = lane & 15;                      // A row id / B col / out col
  const int kg4  = lane >> 4;                      // k-group: k = 8*kg4 + t
  const int cw   = 2 * wv + kg4;                   // logical 16B chunk this lane reads
  const int q7   = q & 7;
  // B slot: need w[kh, 8*kg4 - q + t]; clamp to zero-slot 22
  const int e    = 8 * kg4 - q;
  const int s    = (e >= -7 && e <= 14) ? e + 7 : 22;
  const unsigned short* bbase = &btab[s * 8];
  const int ocol = col0 + wv * 16 + q;

  #pragma unroll
  for (int t = 0; t < NT; ++t) {
    const int row0 = rbase + t * TM;

    // issue next tile's loads; they land during the MFMA phase below
    float4 nv[SITER];
    if (t + 1 < NT) {
      #pragma unroll
      for (int k = 0; k < SITER; ++k)
        nv[k] = load_item(x, row0 + TM, col0, tid + 512 * k);
    }

    // compute current tile: per kh = 1 broadcast B-read + 4 swizzled A-reads + 4 MFMAs
    f32x4 acc0 = {bs,bs,bs,bs}, acc1 = {bs,bs,bs,bs};
    f32x4 acc2 = {bs,bs,bs,bs}, acc3 = {bs,bs,bs,bs};
    __builtin_amdgcn_s_setprio(1);
    #pragma unroll
    for (int kh = 0; kh < 15; ++kh) {
      const bf16x8 b = *(const bf16x8*)(bbase + kh * BKH);
      // row r = q + 16m + kh; physical chunk = cw ^ (r&7) = cw ^ ((q7+kh)&7)
      // (invariant in m, so the 4 m-reads remain immediate offsets +16*LSTR)
      const int ch = ((q7 + kh) & 7) ^ cw;
      const unsigned short* ar = &sx[(q + kh) * LSTR + ch * 8];
      acc0 = MFMA16(*(const bf16x8*)(ar + 0  * LSTR), b, acc0);
      acc1 = MFMA16(*(const bf16x8*)(ar + 16 * LSTR), b, acc1);
      acc2 = MFMA16(*(const bf16x8*)(ar + 32 * LSTR), b, acc2);
      acc3 = MFMA16(*(const bf16x8*)(ar + 48 * LSTR), b, acc3);
    }
    __builtin_amdgcn_s_setprio(0);

    // store: C/D layout col=lane&15, row=(lane>>4)*4+reg
    if (ocol < WO) {
      const int orb = row0 + kg4 * 4;
      const f32x4 av[4] = {acc0, acc1, acc2, acc3};
      #pragma unroll
      for (int m = 0; m < 4; ++m) {
        #pragma unroll
        for (int r = 0; r < 4; ++r) {
          const int orow = orb + 16 * m + r;
          if (orow < HO) out[(long)orow * WO + ocol] = av[m][r];
        }
      }
    }

    // rotate the single LDS buffer for the next tile
    if (t + 1 < NT) {
      __syncthreads();                              // everyone done reading sx
      #pragma unroll
      for (int k = 0; k < SITER; ++k) write_item(sx, tid + 512 * k, nv[k]);
      __syncthreads();                              // next tile visible
    }
  }
}

extern "C" void kernel_launch(void* const* d_in, const int* in_sizes, int n_in,
                              void* d_out, int out_size, void* d_ws, size_t ws_size,
                              hipStream_t stream) {
  const float* x    = (const float*)d_in[0];
  const float* w    = (const float*)d_in[1];
  const float* bias = (const float*)d_in[2];
  float* out        = (float*)d_out;

  dim3 grid(32, 32);   // 1024 blocks: 32 col-strips x 32 row-bands (2 tiles each)
  conv2d_swz<<<grid, dim3(512, 1, 1), 0, stream>>>(x, w, bias, out);
}